// Round 4
// baseline (55.390 us; speedup 1.0000x reference)
//
#include <hip/hip_runtime.h>

// Single-level 1D inverse DWT, cyclic boundary, 4-tap synthesis filters.
// x: [32, 64, 16384, 1] f32 -> rows of M=16384; last = row[0:8192], detail = row[8192:16384].
// out[2p] and out[2p+1] are each 2 lp-taps on 'last' + 2 hp-taps on 'det' with
// offsets d in [-2,1] derived from the zero_* scalars (see R0 derivation).
//
// R1: halo via wave shuffles instead of 8 scalar loads/thread.
// R2/R3: NONTEMPORAL stores (via ext_vector_type f32x4 — the builtin rejects
//     HIP_vector_type). Output stream (134 MB/replay) was thrashing the 256 MiB
//     L3 and evicting the input (FETCH_SIZE ~70 MB = half the input re-fetched
//     each replay). nt stores skip L3 allocation -> input stays resident; write
//     traffic is 100% compulsory anyway, so WRITE_SIZE is unchanged.

#define NPRIME 8192
#define FULLM  (2 * NPRIME)

typedef float f32x4 __attribute__((ext_vector_type(4)));

__device__ __forceinline__ float pick4(float a, float b, float c, float d, int off) {
    // window element at (off + 2): off=-2 -> a, -1 -> b, 0 -> c, 1 -> d
    float r = (off <= -2) ? a : b;
    r = (off == 0) ? c : r;
    r = (off >= 1) ? d : r;
    return r;
}

__global__ __launch_bounds__(256) void idwt1d_kernel(
    const float* __restrict__ x,
    const float* __restrict__ lp,
    const float* __restrict__ hp,
    const int* __restrict__ zlp_p,
    const int* __restrict__ zhp_p,
    float* __restrict__ out,
    int nrows)
{
    const int tid = blockIdx.x * blockDim.x + threadIdx.x;
    const int thrPerRow = NPRIME / 4;           // each thread: 4 pairs = 8 outputs
    const int row = tid / thrPerRow;
    if (row >= nrows) return;
    const int p0 = (tid - row * thrPerRow) * 4;
    const int lane = threadIdx.x & 63;

    const int zh = *zhp_p;   // NOTE: per reference, lp path pads with zero_hp
    const int zl = *zlp_p;   //       and hp path pads with zero_lp

    // lp (low) path, zero = zh. Surviving taps land on even upsample indices.
    const int j0e = zh & 1;
    const int d0  = (j0e - zh) / 2;
    const int j0o = 1 - j0e;
    const int d1  = (1 + j0o - zh) / 2;
    const float A0 = lp[3 - j0e], A1 = lp[1 - j0e];
    const float A2 = lp[3 - j0o], A3 = lp[1 - j0o];

    // hp (detail) path, zero = zl. Surviving taps land on odd upsample indices.
    const int j1e = (zl + 1) & 1;
    const int e0  = (j1e - zl - 1) / 2;
    const int j1o = zl & 1;
    const int e1  = (j1o - zl) / 2;
    const float B0 = hp[3 - j1e], B1 = hp[1 - j1e];
    const float B2 = hp[3 - j1o], B3 = hp[1 - j1o];

    const size_t rb = (size_t)row * FULLM;
    const float* lastp = x + rb;
    const float* detp  = lastp + NPRIME;

    const float4 v = *reinterpret_cast<const float4*>(lastp + p0);
    const float4 u = *reinterpret_cast<const float4*>(detp + p0);

    // halo via wave shuffles: lane-1 holds [p0-4..p0-1], lane+1 holds [p0+4..p0+7]
    float wl0 = __shfl_up(v.z, 1), wl1 = __shfl_up(v.w, 1);
    float wl6 = __shfl_down(v.x, 1), wl7 = __shfl_down(v.y, 1);
    float wd0 = __shfl_up(u.z, 1), wd1 = __shfl_up(u.w, 1);
    float wd6 = __shfl_down(u.x, 1), wd7 = __shfl_down(u.y, 1);

    if (lane == 0) {   // previous wave's data (or cyclic wrap at p0==0)
        const int im2 = (p0 == 0) ? (NPRIME - 2) : (p0 - 2);
        const int im1 = (p0 == 0) ? (NPRIME - 1) : (p0 - 1);
        wl0 = lastp[im2]; wl1 = lastp[im1];
        wd0 = detp[im2];  wd1 = detp[im1];
    }
    if (lane == 63) {  // next wave's data (or cyclic wrap at p0+4==NPRIME)
        const int i4 = (p0 + 4 == NPRIME) ? 0 : (p0 + 4);
        const int i5 = (p0 + 4 == NPRIME) ? 1 : (p0 + 5);
        wl6 = lastp[i4]; wl7 = lastp[i5];
        wd6 = detp[i4];  wd7 = detp[i5];
    }

    const float wl[8] = { wl0, wl1, v.x, v.y, v.z, v.w, wl6, wl7 };
    const float wd[8] = { wd0, wd1, u.x, u.y, u.z, u.w, wd6, wd7 };

    // shift windows by the (wave-uniform) runtime offsets via cndmask selects
    float sle[5], slo[5], sde[5], sdo[5];
    #pragma unroll
    for (int i = 0; i < 5; ++i) {
        sle[i] = pick4(wl[i], wl[i+1], wl[i+2], wl[i+3], d0);
        slo[i] = pick4(wl[i], wl[i+1], wl[i+2], wl[i+3], d1);
        sde[i] = pick4(wd[i], wd[i+1], wd[i+2], wd[i+3], e0);
        sdo[i] = pick4(wd[i], wd[i+1], wd[i+2], wd[i+3], e1);
    }

    float r[8];
    #pragma unroll
    for (int k = 0; k < 4; ++k) {
        r[2*k]   = A0 * sle[k] + A1 * sle[k+1] + B0 * sde[k] + B1 * sde[k+1];
        r[2*k+1] = A2 * slo[k] + A3 * slo[k+1] + B2 * sdo[k] + B3 * sdo[k+1];
    }

    // nontemporal float4 stores: skip L3 allocation so the input stays resident
    f32x4* op = reinterpret_cast<f32x4*>(out + rb + 2 * (size_t)p0);
    f32x4 s0; s0.x = r[0]; s0.y = r[1]; s0.z = r[2]; s0.w = r[3];
    f32x4 s1; s1.x = r[4]; s1.y = r[5]; s1.z = r[6]; s1.w = r[7];
    __builtin_nontemporal_store(s0, op);
    __builtin_nontemporal_store(s1, op + 1);
}

extern "C" void kernel_launch(void* const* d_in, const int* in_sizes, int n_in,
                              void* d_out, int out_size, void* d_ws, size_t ws_size,
                              hipStream_t stream) {
    const float* x  = (const float*)d_in[0];
    const float* lp = (const float*)d_in[1];
    const float* hp = (const float*)d_in[2];
    const int* zlp  = (const int*)d_in[3];
    const int* zhp  = (const int*)d_in[4];
    float* out = (float*)d_out;

    const int nrows = in_sizes[0] / FULLM;            // 32*64 = 2048
    const long long total = (long long)nrows * (NPRIME / 4);
    const int block = 256;
    const int grid = (int)((total + block - 1) / block);

    idwt1d_kernel<<<grid, block, 0, stream>>>(x, lp, hp, zlp, zhp, out, nrows);
}

// Round 5
// 46.133 us; speedup vs baseline: 1.2006x; 1.2006x over previous
//
#include <hip/hip_runtime.h>

// Single-level 1D inverse DWT, cyclic boundary, 4-tap synthesis filters.
// x: [32, 64, 16384, 1] f32 -> rows of M=16384; last = row[0:8192], detail = row[8192:16384].
// out[2p] and out[2p+1] are each 2 lp-taps on 'last' + 2 hp-taps on 'det' with
// offsets d in [-2,1] derived from the zero_* scalars (see R0 derivation).
//
// R1: halo via wave shuffles instead of 8 scalar loads/thread (vmem 12 -> 4/thread).
// R4: REVERTED R3's nontemporal stores — nt writes ran ~35% slower (46.2 -> 55.4 us);
//     normal float4 stores + partial L3 read residency = 5.8-6.1 TB/s app-level,
//     ~95% of the 6.29 TB/s measured copy ceiling for this read+write pattern.

#define NPRIME 8192
#define FULLM  (2 * NPRIME)

__device__ __forceinline__ float pick4(float a, float b, float c, float d, int off) {
    // window element at (off + 2): off=-2 -> a, -1 -> b, 0 -> c, 1 -> d
    float r = (off <= -2) ? a : b;
    r = (off == 0) ? c : r;
    r = (off >= 1) ? d : r;
    return r;
}

__global__ __launch_bounds__(256) void idwt1d_kernel(
    const float* __restrict__ x,
    const float* __restrict__ lp,
    const float* __restrict__ hp,
    const int* __restrict__ zlp_p,
    const int* __restrict__ zhp_p,
    float* __restrict__ out,
    int nrows)
{
    const int tid = blockIdx.x * blockDim.x + threadIdx.x;
    const int thrPerRow = NPRIME / 4;           // each thread: 4 pairs = 8 outputs
    const int row = tid / thrPerRow;
    if (row >= nrows) return;
    const int p0 = (tid - row * thrPerRow) * 4;
    const int lane = threadIdx.x & 63;

    const int zh = *zhp_p;   // NOTE: per reference, lp path pads with zero_hp
    const int zl = *zlp_p;   //       and hp path pads with zero_lp

    // lp (low) path, zero = zh. Surviving taps land on even upsample indices.
    const int j0e = zh & 1;
    const int d0  = (j0e - zh) / 2;
    const int j0o = 1 - j0e;
    const int d1  = (1 + j0o - zh) / 2;
    const float A0 = lp[3 - j0e], A1 = lp[1 - j0e];
    const float A2 = lp[3 - j0o], A3 = lp[1 - j0o];

    // hp (detail) path, zero = zl. Surviving taps land on odd upsample indices.
    const int j1e = (zl + 1) & 1;
    const int e0  = (j1e - zl - 1) / 2;
    const int j1o = zl & 1;
    const int e1  = (j1o - zl) / 2;
    const float B0 = hp[3 - j1e], B1 = hp[1 - j1e];
    const float B2 = hp[3 - j1o], B3 = hp[1 - j1o];

    const size_t rb = (size_t)row * FULLM;
    const float* lastp = x + rb;
    const float* detp  = lastp + NPRIME;

    const float4 v = *reinterpret_cast<const float4*>(lastp + p0);
    const float4 u = *reinterpret_cast<const float4*>(detp + p0);

    // halo via wave shuffles: lane-1 holds [p0-4..p0-1], lane+1 holds [p0+4..p0+7]
    float wl0 = __shfl_up(v.z, 1), wl1 = __shfl_up(v.w, 1);
    float wl6 = __shfl_down(v.x, 1), wl7 = __shfl_down(v.y, 1);
    float wd0 = __shfl_up(u.z, 1), wd1 = __shfl_up(u.w, 1);
    float wd6 = __shfl_down(u.x, 1), wd7 = __shfl_down(u.y, 1);

    if (lane == 0) {   // previous wave's data (or cyclic wrap at p0==0)
        const int im2 = (p0 == 0) ? (NPRIME - 2) : (p0 - 2);
        const int im1 = (p0 == 0) ? (NPRIME - 1) : (p0 - 1);
        wl0 = lastp[im2]; wl1 = lastp[im1];
        wd0 = detp[im2];  wd1 = detp[im1];
    }
    if (lane == 63) {  // next wave's data (or cyclic wrap at p0+4==NPRIME)
        const int i4 = (p0 + 4 == NPRIME) ? 0 : (p0 + 4);
        const int i5 = (p0 + 4 == NPRIME) ? 1 : (p0 + 5);
        wl6 = lastp[i4]; wl7 = lastp[i5];
        wd6 = detp[i4];  wd7 = detp[i5];
    }

    const float wl[8] = { wl0, wl1, v.x, v.y, v.z, v.w, wl6, wl7 };
    const float wd[8] = { wd0, wd1, u.x, u.y, u.z, u.w, wd6, wd7 };

    // shift windows by the (wave-uniform) runtime offsets via cndmask selects
    float sle[5], slo[5], sde[5], sdo[5];
    #pragma unroll
    for (int i = 0; i < 5; ++i) {
        sle[i] = pick4(wl[i], wl[i+1], wl[i+2], wl[i+3], d0);
        slo[i] = pick4(wl[i], wl[i+1], wl[i+2], wl[i+3], d1);
        sde[i] = pick4(wd[i], wd[i+1], wd[i+2], wd[i+3], e0);
        sdo[i] = pick4(wd[i], wd[i+1], wd[i+2], wd[i+3], e1);
    }

    float r[8];
    #pragma unroll
    for (int k = 0; k < 4; ++k) {
        r[2*k]   = A0 * sle[k] + A1 * sle[k+1] + B0 * sde[k] + B1 * sde[k+1];
        r[2*k+1] = A2 * slo[k] + A3 * slo[k+1] + B2 * sdo[k] + B3 * sdo[k+1];
    }

    float* op = out + rb + 2 * (size_t)p0;
    reinterpret_cast<float4*>(op)[0] = make_float4(r[0], r[1], r[2], r[3]);
    reinterpret_cast<float4*>(op)[1] = make_float4(r[4], r[5], r[6], r[7]);
}

extern "C" void kernel_launch(void* const* d_in, const int* in_sizes, int n_in,
                              void* d_out, int out_size, void* d_ws, size_t ws_size,
                              hipStream_t stream) {
    const float* x  = (const float*)d_in[0];
    const float* lp = (const float*)d_in[1];
    const float* hp = (const float*)d_in[2];
    const int* zlp  = (const int*)d_in[3];
    const int* zhp  = (const int*)d_in[4];
    float* out = (float*)d_out;

    const int nrows = in_sizes[0] / FULLM;            // 32*64 = 2048
    const long long total = (long long)nrows * (NPRIME / 4);
    const int block = 256;
    const int grid = (int)((total + block - 1) / block);

    idwt1d_kernel<<<grid, block, 0, stream>>>(x, lp, hp, zlp, zhp, out, nrows);
}